// Round 6
// baseline (249.111 us; speedup 1.0000x reference)
//
#include <hip/hip_runtime.h>
#include <hip/hip_bf16.h>

// BertCRFTagger — B=32, S=512, H=1024, T=32.
//  K0 wpack:      W (1024x32 fp32) -> Wpk bf16 transposed [t][k] (one dwordx4
//                 per B-fragment in the MFMA GEMV).
//  K1 emis_fused: MFMA GEMV (M=16384,K=1024,N=32) + fused log_softmax epilogue.
//                 R5's split version: emis 47.5us (latency-bound, VALUBusy 14%)
//                 + softmax kernel + 8MB part round-trip. One wave = 16 rows,
//                 64x mfma_16x16x32_bf16 over K, 2-stage prefetch (~16KB/CU in
//                 flight > 9KB Little's-law need for HBM saturation).
//  K2 num:        CRF numerator per batch (one 64-thr block/batch, no atomics).
//  K3 chunk:      MFMA chunk transfer matrices (R5, verified absmax 0.0).
//  K4 phase2:     one wave per batch, prefetched chunk sweep, atomic finalize.

#define Bb 32
#define Ss 512
#define Hh 1024
#define Tt 32
#define NROWS (Bb*Ss)          // 16384
#define NCHUNK 32
#define CHUNK_L 16

typedef __attribute__((ext_vector_type(8))) short bf16x8;
typedef __attribute__((ext_vector_type(4))) float f32x4;

__device__ __forceinline__ short f2bf(float f) {  // RNE fp32->bf16
  union { float f; unsigned u; } v; v.f = f;
  unsigned u = v.u;
  return (short)((u + 0x7FFFu + ((u >> 16) & 1u)) >> 16);
}

// ---------------- K0: pack W -> bf16 transposed [t][k] ----------------
__global__ __launch_bounds__(1024) void wpack_kernel(
    const float* __restrict__ W, short* __restrict__ Wpk) {
  const int k = threadIdx.x;  // 1024 threads = k index
#pragma unroll
  for (int t = 0; t < 32; ++t)
    Wpk[t * Hh + k] = f2bf(W[k * 32 + t]);  // coalesced writes per t
}

// ---------------- K1: fused MFMA emissions + log_softmax ----------------
// grid 256 x 256thr. Wave wv handles rows row0..row0+15 (row0 = bx*64+wv*16).
// A[m=lane&15][k=(lane>>4)*8+j]; B[k][n=lane&15]; C/D col=lane&15,row=q*4+r
// (all verified on gfx950 by R5 chunk kernel, absmax 0.0).
__global__ __launch_bounds__(256) void emis_fused_kernel(
    const float* __restrict__ hidden, const short* __restrict__ Wpk,
    const float* __restrict__ bias, float* __restrict__ logem,
    float* __restrict__ pem) {
  const int tid = threadIdx.x;
  const int wv = tid >> 6, lane = tid & 63;
  const int n = lane & 15, q = lane >> 4;
  const int row0 = blockIdx.x * 64 + wv * 16;

  const float* ap = hidden + (size_t)(row0 + n) * Hh + 8 * q;  // lane's 8 floats/chunk
  const short* bpl = Wpk + n * Hh + 8 * q;                     // B left  (cols 0-15)
  const short* bpr = Wpk + (16 + n) * Hh + 8 * q;              // B right (cols 16-31)

  f32x4 d0 = {0.f, 0.f, 0.f, 0.f}, d1 = {0.f, 0.f, 0.f, 0.f};

  float4 ha[2], hb[2];
  bf16x8 wl[2], wr[2];
  ha[0] = *(const float4*)(ap);
  hb[0] = *(const float4*)(ap + 4);
  wl[0] = *(const bf16x8*)(bpl);
  wr[0] = *(const bf16x8*)(bpr);

  for (int kc = 0; kc < 32; ++kc) {
    const int cur = kc & 1, nxt = cur ^ 1;
    if (kc + 1 < 32) {  // prefetch next K-chunk while current computes
      const int off = (kc + 1) * 32;
      ha[nxt] = *(const float4*)(ap + off);
      hb[nxt] = *(const float4*)(ap + off + 4);
      wl[nxt] = *(const bf16x8*)(bpl + off);
      wr[nxt] = *(const bf16x8*)(bpr + off);
    }
    bf16x8 a;
    a[0] = f2bf(ha[cur].x); a[1] = f2bf(ha[cur].y);
    a[2] = f2bf(ha[cur].z); a[3] = f2bf(ha[cur].w);
    a[4] = f2bf(hb[cur].x); a[5] = f2bf(hb[cur].y);
    a[6] = f2bf(hb[cur].z); a[7] = f2bf(hb[cur].w);
    d0 = __builtin_amdgcn_mfma_f32_16x16x32_bf16(a, wl[cur], d0, 0, 0, 0);
    d1 = __builtin_amdgcn_mfma_f32_16x16x32_bf16(a, wr[cur], d1, 0, 0, 0);
  }

  // Fused log_softmax epilogue. Row 4q+r spread over 16 lanes (n=0..15), 2 cols
  // per lane (d0: col n, d1: col 16+n). Width-16 shfl keeps the q-group.
  const float bn = bias[n], bn2 = bias[16 + n];
#pragma unroll
  for (int r = 0; r < 4; ++r) {
    const float L0 = d0[r] + bn, L1 = d1[r] + bn2;
    float mx = fmaxf(L0, L1);
#pragma unroll
    for (int d = 8; d >= 1; d >>= 1) mx = fmaxf(mx, __shfl_xor(mx, d, 16));
    float se = __expf(L0 - mx) + __expf(L1 - mx);
#pragma unroll
    for (int d = 8; d >= 1; d >>= 1) se += __shfl_xor(se, d, 16);
    const float corr = mx + __logf(se);
    const float lg0 = L0 - corr, lg1 = L1 - corr;
    const size_t rb = (size_t)(row0 + 4 * q + r) * Tt;
    logem[rb + n] = lg0;
    logem[rb + 16 + n] = lg1;
    pem[rb + n] = __expf(lg0);
    pem[rb + 16 + n] = __expf(lg1);
  }
}

// ---------------- K2: numerator + lengths (one block/batch, no atomics) ----
__global__ __launch_bounds__(64) void num_kernel(
    const float* __restrict__ logem, const float* __restrict__ start_trans,
    const float* __restrict__ trans, const int* __restrict__ tags,
    const int* __restrict__ mask, float* __restrict__ numb,
    int* __restrict__ lenw) {
  const int b = blockIdx.x;
  const int l = threadIdx.x;
  const int base = b * Ss;
  int lensum = 0;
  float s = 0.f;
#pragma unroll
  for (int k = 0; k < 8; ++k) {
    int ss = l + 64 * k;
    int m = mask[base + ss];
    lensum += m;
    if (m) {
      int tg = tags[base + ss];
      s += logem[(size_t)(base + ss) * Tt + tg];
      if (ss > 0) s += trans[tags[base + ss - 1] * Tt + tg];
    }
  }
#pragma unroll
  for (int d = 32; d >= 1; d >>= 1) {
    s += __shfl_xor(s, d);
    lensum += __shfl_xor(lensum, d);
  }
  if (l == 0) {
    numb[b] = s + start_trans[tags[base]];  // end_trans added in phase2
    lenw[b] = lensum;
  }
}

// ---------------- K3: chunk transfer matrices via MFMA (R5, verified) -------
__global__ __launch_bounds__(256) void chunk_kernel(
    const float* __restrict__ pem, const float* __restrict__ trans,
    const int* __restrict__ lenw, float* __restrict__ ecT,
    float* __restrict__ moff) {
  __shared__ __align__(16) float Pbuf[4 * 32 * 36];
  const int tid = threadIdx.x;
  const int wv = tid >> 6, lane = tid & 63;
  const int n = lane & 15, q = lane >> 4;
  const int chunk = blockIdx.x * 4 + wv;
  const int b = chunk >> 5, cc = chunk & 31;
  float* P = Pbuf + wv * 32 * 36;

  float etr0[8], etr1[8];
#pragma unroll
  for (int jj = 0; jj < 8; ++jj) {
    etr0[jj] = __expf(trans[(8 * q + jj) * 32 + n]);
    etr1[jj] = __expf(trans[(8 * q + jj) * 32 + 16 + n]);
  }

  const int len = lenw[b];
  const int t0 = 1 + cc * CHUNK_L;
  int nst = (len < Ss ? len : Ss) - t0;
  nst = nst < 0 ? 0 : (nst > CHUNK_L ? CHUNK_L : nst);
  const int rowbase = b * Ss + t0;

  bf16x8 a0, a1;
#pragma unroll
  for (int jj = 0; jj < 8; ++jj) {
    a0[jj] = (n == 8 * q + jj) ? (short)0x3F80 : (short)0;
    a1[jj] = (16 + n == 8 * q + jj) ? (short)0x3F80 : (short)0;
  }

  f32x4 d00, d01, d10, d11;
  if (nst == 0) {
#pragma unroll
    for (int r = 0; r < 4; ++r) {
      d00[r] = (4 * q + r == n) ? 1.f : 0.f;
      d01[r] = 0.f;
      d10[r] = 0.f;
      d11[r] = (4 * q + r == n) ? 1.f : 0.f;
    }
  }
  float em0 = 0.f, em1 = 0.f;
  if (nst > 0) {
    em0 = pem[(size_t)rowbase * Tt + n];
    em1 = pem[(size_t)rowbase * Tt + 16 + n];
  }
  for (int st = 0; st < nst; ++st) {
    float em0n = 0.f, em1n = 0.f;
    if (st + 1 < nst) {
      em0n = pem[(size_t)(rowbase + st + 1) * Tt + n];
      em1n = pem[(size_t)(rowbase + st + 1) * Tt + 16 + n];
    }
    bf16x8 bL, bR;
#pragma unroll
    for (int jj = 0; jj < 8; ++jj) {
      bL[jj] = f2bf(etr0[jj] * em0);
      bR[jj] = f2bf(etr1[jj] * em1);
    }
    const f32x4 z = {0.f, 0.f, 0.f, 0.f};
    d00 = __builtin_amdgcn_mfma_f32_16x16x32_bf16(a0, bL, z, 0, 0, 0);
    d01 = __builtin_amdgcn_mfma_f32_16x16x32_bf16(a0, bR, z, 0, 0, 0);
    d10 = __builtin_amdgcn_mfma_f32_16x16x32_bf16(a1, bL, z, 0, 0, 0);
    d11 = __builtin_amdgcn_mfma_f32_16x16x32_bf16(a1, bR, z, 0, 0, 0);
    if (st + 1 < nst) {
#pragma unroll
      for (int r = 0; r < 4; ++r) {
        P[(4 * q + r) * 36 + n] = d00[r];
        P[(4 * q + r) * 36 + 16 + n] = d01[r];
        P[(16 + 4 * q + r) * 36 + n] = d10[r];
        P[(16 + 4 * q + r) * 36 + 16 + n] = d11[r];
      }
      __builtin_amdgcn_s_waitcnt(0);
      const float4 lo0 = *(const float4*)&P[n * 36 + 8 * q];
      const float4 lo1 = *(const float4*)&P[n * 36 + 8 * q + 4];
      const float4 hi0 = *(const float4*)&P[(16 + n) * 36 + 8 * q];
      const float4 hi1 = *(const float4*)&P[(16 + n) * 36 + 8 * q + 4];
      a0[0] = f2bf(lo0.x); a0[1] = f2bf(lo0.y); a0[2] = f2bf(lo0.z); a0[3] = f2bf(lo0.w);
      a0[4] = f2bf(lo1.x); a0[5] = f2bf(lo1.y); a0[6] = f2bf(lo1.z); a0[7] = f2bf(lo1.w);
      a1[0] = f2bf(hi0.x); a1[1] = f2bf(hi0.y); a1[2] = f2bf(hi0.z); a1[3] = f2bf(hi0.w);
      a1[4] = f2bf(hi1.x); a1[5] = f2bf(hi1.y); a1[6] = f2bf(hi1.z); a1[7] = f2bf(hi1.w);
    }
    em0 = em0n; em1 = em1n;
  }

  float lg0[4], lg1[4], iv0[4], iv1[4];
#pragma unroll
  for (int r = 0; r < 4; ++r) {
    float m0v = fmaxf(d00[r], d01[r]);
    float m1v = fmaxf(d10[r], d11[r]);
#pragma unroll
    for (int d = 8; d >= 1; d >>= 1) {
      m0v = fmaxf(m0v, __shfl_xor(m0v, d, 16));
      m1v = fmaxf(m1v, __shfl_xor(m1v, d, 16));
    }
    m0v = fmaxf(m0v, 1e-37f);
    m1v = fmaxf(m1v, 1e-37f);
    lg0[r] = __logf(m0v); iv0[r] = __builtin_amdgcn_rcpf(m0v);
    lg1[r] = __logf(m1v); iv1[r] = __builtin_amdgcn_rcpf(m1v);
  }
  float* E = ecT + (size_t)(b * NCHUNK + cc) * 32 * 32;
  {
    float4 s;
    s = make_float4(d00[0] * iv0[0], d00[1] * iv0[1], d00[2] * iv0[2], d00[3] * iv0[3]);
    *(float4*)&E[n * 32 + 4 * q] = s;
    s = make_float4(d10[0] * iv1[0], d10[1] * iv1[1], d10[2] * iv1[2], d10[3] * iv1[3]);
    *(float4*)&E[n * 32 + 16 + 4 * q] = s;
    s = make_float4(d01[0] * iv0[0], d01[1] * iv0[1], d01[2] * iv0[2], d01[3] * iv0[3]);
    *(float4*)&E[(16 + n) * 32 + 4 * q] = s;
    s = make_float4(d11[0] * iv1[0], d11[1] * iv1[1], d11[2] * iv1[2], d11[3] * iv1[3]);
    *(float4*)&E[(16 + n) * 32 + 16 + 4 * q] = s;
  }
  if (n == 0) {
    float* Mo = moff + (size_t)(b * NCHUNK + cc) * 32;
    *(float4*)&Mo[4 * q] = make_float4(lg0[0], lg0[1], lg0[2], lg0[3]);
    *(float4*)&Mo[16 + 4 * q] = make_float4(lg1[0], lg1[1], lg1[2], lg1[3]);
  }
}

// ---------------- K4: phase-2 sweep, one wave per batch ----------------
__global__ __launch_bounds__(64) void phase2_kernel(
    const float* __restrict__ logem, const float* __restrict__ start_trans,
    const float* __restrict__ end_trans, const float* __restrict__ ecT,
    const float* __restrict__ moff, const float* __restrict__ numb,
    const int* __restrict__ lenw, const int* __restrict__ tags,
    float* __restrict__ out) {
  const int b = blockIdx.x;
  const int lane = threadIdx.x;
  const int j = lane & 31;
  __shared__ __align__(16) float qlds[32];

  const float* base = ecT + (size_t)b * NCHUNK * 32 * 32;
  const float* mbase = moff + (size_t)b * NCHUNK * 32;

  float4 M[8], N[8];
  const float* r0 = base + j * 32;
#pragma unroll
  for (int k = 0; k < 8; ++k) M[k] = *(const float4*)(r0 + 4 * k);
  float mo_cur = mbase[j];

  float al0 = start_trans[j] + logem[(size_t)b * Ss * Tt + j];
  float m0 = al0;
#pragma unroll
  for (int d = 16; d >= 1; d >>= 1) m0 = fmaxf(m0, __shfl_xor(m0, d, 32));
  float a = __expf(al0 - m0);
  float Mb = m0;
  const float eend = __expf(end_trans[j]);

  float mo_next = 0.f;
  for (int c = 0; c < NCHUNK; ++c) {
    if (c + 1 < NCHUNK) {
      const float* rn = base + ((c + 1) * 32 + j) * 32;
#pragma unroll
      for (int k = 0; k < 8; ++k) N[k] = *(const float4*)(rn + 4 * k);
      mo_next = mbase[(c + 1) * 32 + j];
    }
    float mom = mo_cur;
#pragma unroll
    for (int d = 16; d >= 1; d >>= 1) mom = fmaxf(mom, __shfl_xor(mom, d, 32));
    float q = a * __expf(mo_cur - mom);
    if (lane < 32) qlds[j] = q;
    __builtin_amdgcn_s_waitcnt(0);
    float s = 0.f;
#pragma unroll
    for (int k = 0; k < 8; ++k) {
      const float4 q4 = *(const float4*)(qlds + 4 * k);
      s = fmaf(q4.x, M[k].x, s);
      s = fmaf(q4.y, M[k].y, s);
      s = fmaf(q4.z, M[k].z, s);
      s = fmaf(q4.w, M[k].w, s);
    }
    float m = s;
#pragma unroll
    for (int d = 16; d >= 1; d >>= 1) m = fmaxf(m, __shfl_xor(m, d, 32));
    m = fmaxf(m, 1e-30f);
    a = s * __builtin_amdgcn_rcpf(m);
    Mb += mom + __logf(m);
#pragma unroll
    for (int k = 0; k < 8; ++k) M[k] = N[k];
    mo_cur = mo_next;
  }
  float z = a * eend;
#pragma unroll
  for (int d = 16; d >= 1; d >>= 1) z += __shfl_xor(z, d, 32);
  if (lane == 0) {
    const int len = lenw[b];
    const float numfull = numb[b] + end_trans[tags[b * Ss + len - 1]];
    const float denom = Mb + __logf(z);
    atomicAdd(out, -(numfull - denom) * (1.0f / 32.0f));
  }
}

extern "C" void kernel_launch(void* const* d_in, const int* in_sizes, int n_in,
                              void* d_out, int out_size, void* d_ws, size_t ws_size,
                              hipStream_t stream) {
  const float* hidden = (const float*)d_in[0];
  const float* W = (const float*)d_in[1];
  const float* bias = (const float*)d_in[2];
  const float* start_trans = (const float*)d_in[3];
  const float* end_trans = (const float*)d_in[4];
  const float* trans = (const float*)d_in[5];
  const int* tags = (const int*)d_in[6];
  const int* mask = (const int*)d_in[7];
  float* out = (float*)d_out;

  float* logem = (float*)d_ws;                       // 524288
  float* pem = logem + (size_t)NROWS * Tt;           // 524288
  float* ecT = pem + (size_t)NROWS * Tt;             // 1048576
  float* moff = ecT + (size_t)Bb * NCHUNK * 32 * 32; // 32768
  float* numb = moff + (size_t)Bb * NCHUNK * 32;     // 32
  int* lenw = (int*)(numb + Bb);                     // 32
  short* Wpk = (short*)(lenw + Bb);                  // 32768 shorts (16B-aligned)

  hipMemsetAsync(out, 0, sizeof(float), stream);
  wpack_kernel<<<1, 1024, 0, stream>>>(W, Wpk);
  emis_fused_kernel<<<NROWS / 64, 256, 0, stream>>>(hidden, Wpk, bias, logem, pem);
  num_kernel<<<Bb, 64, 0, stream>>>(logem, start_trans, trans, tags, mask, numb,
                                    lenw);
  chunk_kernel<<<Bb * NCHUNK / 4, 256, 0, stream>>>(pem, trans, lenw, ecT, moff);
  phase2_kernel<<<Bb, 64, 0, stream>>>(logem, start_trans, end_trans, ecT, moff,
                                       numb, lenw, tags, out);
}

// Round 7
// 172.661 us; speedup vs baseline: 1.4428x; 1.4428x over previous
//
#include <hip/hip_runtime.h>
#include <hip/hip_bf16.h>

// BertCRFTagger — B=32, S=512, H=1024, T=32.
//  K0 wpack:      W -> bf16 transposed [t][k].
//  K1 emis_fused: MFMA GEMV + fused log_softmax, SPLIT-K x4.
//                 R6 failure: 1 wave/16-row-tile over full K -> 1024 waves =
//                 4 waves/CU (Occupancy 9.4%), latency-bound at 322 GB/s.
//                 Now: block = 16 rows, wave w does K in [256w,256w+256),
//                 LDS partial combine (stride 33 = 2-way conflicts, free).
//                 4096 waves = 16/CU -> TLP hides load latency.
//  K2 num:        CRF numerator per batch (one 64-thr block/batch).
//  K3 chunk:      MFMA chunk transfer matrices (verified absmax 0.0).
//  K4 phase2:     one wave per batch, prefetched chunk sweep, atomic finalize.

#define Bb 32
#define Ss 512
#define Hh 1024
#define Tt 32
#define NROWS (Bb*Ss)          // 16384
#define NCHUNK 32
#define CHUNK_L 16

typedef __attribute__((ext_vector_type(8))) short bf16x8;
typedef __attribute__((ext_vector_type(4))) float f32x4;

__device__ __forceinline__ short f2bf(float f) {  // RNE fp32->bf16
  union { float f; unsigned u; } v; v.f = f;
  unsigned u = v.u;
  return (short)((u + 0x7FFFu + ((u >> 16) & 1u)) >> 16);
}

// ---------------- K0: pack W -> bf16 transposed [t][k] ----------------
__global__ __launch_bounds__(1024) void wpack_kernel(
    const float* __restrict__ W, short* __restrict__ Wpk) {
  const int k = threadIdx.x;
#pragma unroll
  for (int t = 0; t < 32; ++t)
    Wpk[t * Hh + k] = f2bf(W[k * 32 + t]);
}

// ---------------- K1: fused MFMA emissions + log_softmax, split-K ----------
// grid 1024 x 256thr. Block = rows row0..row0+15; wave wv does K quarter wv.
// A[m=lane&15][k=(lane>>4)*8+j]; B[k][n=lane&15]; C/D col=lane&15,row=q*4+r.
__global__ __launch_bounds__(256) void emis_fused_kernel(
    const float* __restrict__ hidden, const short* __restrict__ Wpk,
    const float* __restrict__ bias, float* __restrict__ logem,
    float* __restrict__ pem) {
  __shared__ float red[4 * 16 * 33];  // [wave][row][col], stride 33: 2-way max
  const int tid = threadIdx.x;
  const int wv = tid >> 6, lane = tid & 63;
  const int n = lane & 15, q = lane >> 4;
  const int row0 = blockIdx.x * 16;
  const int koff = wv * 256;

  const float* ap = hidden + (size_t)(row0 + n) * Hh + koff + 8 * q;
  const short* bpl = Wpk + n * Hh + koff + 8 * q;
  const short* bpr = Wpk + (16 + n) * Hh + koff + 8 * q;

  f32x4 d0 = {0.f, 0.f, 0.f, 0.f}, d1 = {0.f, 0.f, 0.f, 0.f};

  float4 ha[2], hb[2];
  bf16x8 wl[2], wr[2];
  ha[0] = *(const float4*)(ap);
  hb[0] = *(const float4*)(ap + 4);
  wl[0] = *(const bf16x8*)(bpl);
  wr[0] = *(const bf16x8*)(bpr);

  for (int kc = 0; kc < 8; ++kc) {
    const int cur = kc & 1, nxt = cur ^ 1;
    if (kc + 1 < 8) {
      const int off = (kc + 1) * 32;
      ha[nxt] = *(const float4*)(ap + off);
      hb[nxt] = *(const float4*)(ap + off + 4);
      wl[nxt] = *(const bf16x8*)(bpl + off);
      wr[nxt] = *(const bf16x8*)(bpr + off);
    }
    bf16x8 a;
    a[0] = f2bf(ha[cur].x); a[1] = f2bf(ha[cur].y);
    a[2] = f2bf(ha[cur].z); a[3] = f2bf(ha[cur].w);
    a[4] = f2bf(hb[cur].x); a[5] = f2bf(hb[cur].y);
    a[6] = f2bf(hb[cur].z); a[7] = f2bf(hb[cur].w);
    d0 = __builtin_amdgcn_mfma_f32_16x16x32_bf16(a, wl[cur], d0, 0, 0, 0);
    d1 = __builtin_amdgcn_mfma_f32_16x16x32_bf16(a, wr[cur], d1, 0, 0, 0);
  }

  // partials -> LDS
#pragma unroll
  for (int r = 0; r < 4; ++r) {
    red[(wv * 16 + 4 * q + r) * 33 + n] = d0[r];
    red[(wv * 16 + 4 * q + r) * 33 + 16 + n] = d1[r];
  }
  __syncthreads();

  // combine + softmax: thread = (row = tid>>4, cols c0 = tid&15, c1 = c0+16).
  // Lanes sharing a row are 16 consecutive -> width-16 shfl reduction.
  const int row = tid >> 4, c0 = tid & 15, c1 = 16 + c0;
  float v0 = 0.f, v1 = 0.f;
#pragma unroll
  for (int w = 0; w < 4; ++w) {
    v0 += red[(w * 16 + row) * 33 + c0];
    v1 += red[(w * 16 + row) * 33 + c1];
  }
  const float L0 = v0 + bias[c0], L1 = v1 + bias[c1];
  float mx = fmaxf(L0, L1);
#pragma unroll
  for (int d = 8; d >= 1; d >>= 1) mx = fmaxf(mx, __shfl_xor(mx, d, 16));
  float se = __expf(L0 - mx) + __expf(L1 - mx);
#pragma unroll
  for (int d = 8; d >= 1; d >>= 1) se += __shfl_xor(se, d, 16);
  const float corr = mx + __logf(se);
  const float lg0 = L0 - corr, lg1 = L1 - corr;
  const size_t rb = (size_t)(row0 + row) * Tt;
  logem[rb + c0] = lg0;
  logem[rb + c1] = lg1;
  pem[rb + c0] = __expf(lg0);
  pem[rb + c1] = __expf(lg1);
}

// ---------------- K2: numerator + lengths (one block/batch) ----------------
__global__ __launch_bounds__(64) void num_kernel(
    const float* __restrict__ logem, const float* __restrict__ start_trans,
    const float* __restrict__ trans, const int* __restrict__ tags,
    const int* __restrict__ mask, float* __restrict__ numb,
    int* __restrict__ lenw) {
  const int b = blockIdx.x;
  const int l = threadIdx.x;
  const int base = b * Ss;
  int lensum = 0;
  float s = 0.f;
#pragma unroll
  for (int k = 0; k < 8; ++k) {
    int ss = l + 64 * k;
    int m = mask[base + ss];
    lensum += m;
    if (m) {
      int tg = tags[base + ss];
      s += logem[(size_t)(base + ss) * Tt + tg];
      if (ss > 0) s += trans[tags[base + ss - 1] * Tt + tg];
    }
  }
#pragma unroll
  for (int d = 32; d >= 1; d >>= 1) {
    s += __shfl_xor(s, d);
    lensum += __shfl_xor(lensum, d);
  }
  if (l == 0) {
    numb[b] = s + start_trans[tags[base]];
    lenw[b] = lensum;
  }
}

// ---------------- K3: chunk transfer matrices via MFMA ----------------
__global__ __launch_bounds__(256) void chunk_kernel(
    const float* __restrict__ pem, const float* __restrict__ trans,
    const int* __restrict__ lenw, float* __restrict__ ecT,
    float* __restrict__ moff) {
  __shared__ __align__(16) float Pbuf[4 * 32 * 36];
  const int tid = threadIdx.x;
  const int wv = tid >> 6, lane = tid & 63;
  const int n = lane & 15, q = lane >> 4;
  const int chunk = blockIdx.x * 4 + wv;
  const int b = chunk >> 5, cc = chunk & 31;
  float* P = Pbuf + wv * 32 * 36;

  float etr0[8], etr1[8];
#pragma unroll
  for (int jj = 0; jj < 8; ++jj) {
    etr0[jj] = __expf(trans[(8 * q + jj) * 32 + n]);
    etr1[jj] = __expf(trans[(8 * q + jj) * 32 + 16 + n]);
  }

  const int len = lenw[b];
  const int t0 = 1 + cc * CHUNK_L;
  int nst = (len < Ss ? len : Ss) - t0;
  nst = nst < 0 ? 0 : (nst > CHUNK_L ? CHUNK_L : nst);
  const int rowbase = b * Ss + t0;

  bf16x8 a0, a1;
#pragma unroll
  for (int jj = 0; jj < 8; ++jj) {
    a0[jj] = (n == 8 * q + jj) ? (short)0x3F80 : (short)0;
    a1[jj] = (16 + n == 8 * q + jj) ? (short)0x3F80 : (short)0;
  }

  f32x4 d00, d01, d10, d11;
  if (nst == 0) {
#pragma unroll
    for (int r = 0; r < 4; ++r) {
      d00[r] = (4 * q + r == n) ? 1.f : 0.f;
      d01[r] = 0.f;
      d10[r] = 0.f;
      d11[r] = (4 * q + r == n) ? 1.f : 0.f;
    }
  }
  float em0 = 0.f, em1 = 0.f;
  if (nst > 0) {
    em0 = pem[(size_t)rowbase * Tt + n];
    em1 = pem[(size_t)rowbase * Tt + 16 + n];
  }
  for (int st = 0; st < nst; ++st) {
    float em0n = 0.f, em1n = 0.f;
    if (st + 1 < nst) {
      em0n = pem[(size_t)(rowbase + st + 1) * Tt + n];
      em1n = pem[(size_t)(rowbase + st + 1) * Tt + 16 + n];
    }
    bf16x8 bL, bR;
#pragma unroll
    for (int jj = 0; jj < 8; ++jj) {
      bL[jj] = f2bf(etr0[jj] * em0);
      bR[jj] = f2bf(etr1[jj] * em1);
    }
    const f32x4 z = {0.f, 0.f, 0.f, 0.f};
    d00 = __builtin_amdgcn_mfma_f32_16x16x32_bf16(a0, bL, z, 0, 0, 0);
    d01 = __builtin_amdgcn_mfma_f32_16x16x32_bf16(a0, bR, z, 0, 0, 0);
    d10 = __builtin_amdgcn_mfma_f32_16x16x32_bf16(a1, bL, z, 0, 0, 0);
    d11 = __builtin_amdgcn_mfma_f32_16x16x32_bf16(a1, bR, z, 0, 0, 0);
    if (st + 1 < nst) {
#pragma unroll
      for (int r = 0; r < 4; ++r) {
        P[(4 * q + r) * 36 + n] = d00[r];
        P[(4 * q + r) * 36 + 16 + n] = d01[r];
        P[(16 + 4 * q + r) * 36 + n] = d10[r];
        P[(16 + 4 * q + r) * 36 + 16 + n] = d11[r];
      }
      __builtin_amdgcn_s_waitcnt(0);
      const float4 lo0 = *(const float4*)&P[n * 36 + 8 * q];
      const float4 lo1 = *(const float4*)&P[n * 36 + 8 * q + 4];
      const float4 hi0 = *(const float4*)&P[(16 + n) * 36 + 8 * q];
      const float4 hi1 = *(const float4*)&P[(16 + n) * 36 + 8 * q + 4];
      a0[0] = f2bf(lo0.x); a0[1] = f2bf(lo0.y); a0[2] = f2bf(lo0.z); a0[3] = f2bf(lo0.w);
      a0[4] = f2bf(lo1.x); a0[5] = f2bf(lo1.y); a0[6] = f2bf(lo1.z); a0[7] = f2bf(lo1.w);
      a1[0] = f2bf(hi0.x); a1[1] = f2bf(hi0.y); a1[2] = f2bf(hi0.z); a1[3] = f2bf(hi0.w);
      a1[4] = f2bf(hi1.x); a1[5] = f2bf(hi1.y); a1[6] = f2bf(hi1.z); a1[7] = f2bf(hi1.w);
    }
    em0 = em0n; em1 = em1n;
  }

  float lg0[4], lg1[4], iv0[4], iv1[4];
#pragma unroll
  for (int r = 0; r < 4; ++r) {
    float m0v = fmaxf(d00[r], d01[r]);
    float m1v = fmaxf(d10[r], d11[r]);
#pragma unroll
    for (int d = 8; d >= 1; d >>= 1) {
      m0v = fmaxf(m0v, __shfl_xor(m0v, d, 16));
      m1v = fmaxf(m1v, __shfl_xor(m1v, d, 16));
    }
    m0v = fmaxf(m0v, 1e-37f);
    m1v = fmaxf(m1v, 1e-37f);
    lg0[r] = __logf(m0v); iv0[r] = __builtin_amdgcn_rcpf(m0v);
    lg1[r] = __logf(m1v); iv1[r] = __builtin_amdgcn_rcpf(m1v);
  }
  float* E = ecT + (size_t)(b * NCHUNK + cc) * 32 * 32;
  {
    float4 s;
    s = make_float4(d00[0] * iv0[0], d00[1] * iv0[1], d00[2] * iv0[2], d00[3] * iv0[3]);
    *(float4*)&E[n * 32 + 4 * q] = s;
    s = make_float4(d10[0] * iv1[0], d10[1] * iv1[1], d10[2] * iv1[2], d10[3] * iv1[3]);
    *(float4*)&E[n * 32 + 16 + 4 * q] = s;
    s = make_float4(d01[0] * iv0[0], d01[1] * iv0[1], d01[2] * iv0[2], d01[3] * iv0[3]);
    *(float4*)&E[(16 + n) * 32 + 4 * q] = s;
    s = make_float4(d11[0] * iv1[0], d11[1] * iv1[1], d11[2] * iv1[2], d11[3] * iv1[3]);
    *(float4*)&E[(16 + n) * 32 + 16 + 4 * q] = s;
  }
  if (n == 0) {
    float* Mo = moff + (size_t)(b * NCHUNK + cc) * 32;
    *(float4*)&Mo[4 * q] = make_float4(lg0[0], lg0[1], lg0[2], lg0[3]);
    *(float4*)&Mo[16 + 4 * q] = make_float4(lg1[0], lg1[1], lg1[2], lg1[3]);
  }
}

// ---------------- K4: phase-2 sweep, one wave per batch ----------------
__global__ __launch_bounds__(64) void phase2_kernel(
    const float* __restrict__ logem, const float* __restrict__ start_trans,
    const float* __restrict__ end_trans, const float* __restrict__ ecT,
    const float* __restrict__ moff, const float* __restrict__ numb,
    const int* __restrict__ lenw, const int* __restrict__ tags,
    float* __restrict__ out) {
  const int b = blockIdx.x;
  const int lane = threadIdx.x;
  const int j = lane & 31;
  __shared__ __align__(16) float qlds[32];

  const float* base = ecT + (size_t)b * NCHUNK * 32 * 32;
  const float* mbase = moff + (size_t)b * NCHUNK * 32;

  float4 M[8], N[8];
  const float* r0 = base + j * 32;
#pragma unroll
  for (int k = 0; k < 8; ++k) M[k] = *(const float4*)(r0 + 4 * k);
  float mo_cur = mbase[j];

  float al0 = start_trans[j] + logem[(size_t)b * Ss * Tt + j];
  float m0 = al0;
#pragma unroll
  for (int d = 16; d >= 1; d >>= 1) m0 = fmaxf(m0, __shfl_xor(m0, d, 32));
  float a = __expf(al0 - m0);
  float Mb = m0;
  const float eend = __expf(end_trans[j]);

  float mo_next = 0.f;
  for (int c = 0; c < NCHUNK; ++c) {
    if (c + 1 < NCHUNK) {
      const float* rn = base + ((c + 1) * 32 + j) * 32;
#pragma unroll
      for (int k = 0; k < 8; ++k) N[k] = *(const float4*)(rn + 4 * k);
      mo_next = mbase[(c + 1) * 32 + j];
    }
    float mom = mo_cur;
#pragma unroll
    for (int d = 16; d >= 1; d >>= 1) mom = fmaxf(mom, __shfl_xor(mom, d, 32));
    float q = a * __expf(mo_cur - mom);
    if (lane < 32) qlds[j] = q;
    __builtin_amdgcn_s_waitcnt(0);
    float s = 0.f;
#pragma unroll
    for (int k = 0; k < 8; ++k) {
      const float4 q4 = *(const float4*)(qlds + 4 * k);
      s = fmaf(q4.x, M[k].x, s);
      s = fmaf(q4.y, M[k].y, s);
      s = fmaf(q4.z, M[k].z, s);
      s = fmaf(q4.w, M[k].w, s);
    }
    float m = s;
#pragma unroll
    for (int d = 16; d >= 1; d >>= 1) m = fmaxf(m, __shfl_xor(m, d, 32));
    m = fmaxf(m, 1e-30f);
    a = s * __builtin_amdgcn_rcpf(m);
    Mb += mom + __logf(m);
#pragma unroll
    for (int k = 0; k < 8; ++k) M[k] = N[k];
    mo_cur = mo_next;
  }
  float z = a * eend;
#pragma unroll
  for (int d = 16; d >= 1; d >>= 1) z += __shfl_xor(z, d, 32);
  if (lane == 0) {
    const int len = lenw[b];
    const float numfull = numb[b] + end_trans[tags[b * Ss + len - 1]];
    const float denom = Mb + __logf(z);
    atomicAdd(out, -(numfull - denom) * (1.0f / 32.0f));
  }
}

extern "C" void kernel_launch(void* const* d_in, const int* in_sizes, int n_in,
                              void* d_out, int out_size, void* d_ws, size_t ws_size,
                              hipStream_t stream) {
  const float* hidden = (const float*)d_in[0];
  const float* W = (const float*)d_in[1];
  const float* bias = (const float*)d_in[2];
  const float* start_trans = (const float*)d_in[3];
  const float* end_trans = (const float*)d_in[4];
  const float* trans = (const float*)d_in[5];
  const int* tags = (const int*)d_in[6];
  const int* mask = (const int*)d_in[7];
  float* out = (float*)d_out;

  float* logem = (float*)d_ws;                       // 524288
  float* pem = logem + (size_t)NROWS * Tt;           // 524288
  float* ecT = pem + (size_t)NROWS * Tt;             // 1048576
  float* moff = ecT + (size_t)Bb * NCHUNK * 32 * 32; // 32768
  float* numb = moff + (size_t)Bb * NCHUNK * 32;     // 32
  int* lenw = (int*)(numb + Bb);                     // 32
  short* Wpk = (short*)(lenw + Bb);                  // 32768 shorts

  hipMemsetAsync(out, 0, sizeof(float), stream);
  wpack_kernel<<<1, 1024, 0, stream>>>(W, Wpk);
  emis_fused_kernel<<<NROWS / 16, 256, 0, stream>>>(hidden, Wpk, bias, logem, pem);
  num_kernel<<<Bb, 64, 0, stream>>>(logem, start_trans, trans, tags, mask, numb,
                                    lenw);
  chunk_kernel<<<Bb * NCHUNK / 4, 256, 0, stream>>>(pem, trans, lenw, ecT, moff);
  phase2_kernel<<<Bb, 64, 0, stream>>>(logem, start_trans, end_trans, ecT, moff,
                                       numb, lenw, tags, out);
}

// Round 8
// 169.304 us; speedup vs baseline: 1.4714x; 1.0198x over previous
//
#include <hip/hip_runtime.h>
#include <hip/hip_bf16.h>

// BertCRFTagger — B=32, S=512, H=1024, T=32.
//  K0 wpack:      W -> bf16 transposed [t][k]; thread 0 also zeroes out
//                 (drops the memset dispatch).
//  K1 emis_fused: MFMA GEMV + fused log_softmax, split-K x4, 4-deep prefetch
//                 (R7 was 2-deep; emis ~30us vs ~10us HBM floor = latency).
//  K2 chunk:      MFMA chunk transfer matrices; nst from mask ballot (no lenw
//                 dependency -> numerator can fuse into phase2).
//  K3 phase2:     one wave per batch: fused CRF numerator (width-64 shfl
//                 reduce) + prefetched chunk sweep + atomic finalize.
// Dispatches: 4 (R7 had 6; ~5us dependent-launch gap each).

#define Bb 32
#define Ss 512
#define Hh 1024
#define Tt 32
#define NROWS (Bb*Ss)          // 16384
#define NCHUNK 32
#define CHUNK_L 16

typedef __attribute__((ext_vector_type(8))) short bf16x8;
typedef __attribute__((ext_vector_type(4))) float f32x4;

__device__ __forceinline__ short f2bf(float f) {  // RNE fp32->bf16
  union { float f; unsigned u; } v; v.f = f;
  unsigned u = v.u;
  return (short)((u + 0x7FFFu + ((u >> 16) & 1u)) >> 16);
}

// ---------------- K0: pack W -> bf16 [t][k] + zero out ----------------
__global__ __launch_bounds__(1024) void wpack_kernel(
    const float* __restrict__ W, short* __restrict__ Wpk,
    float* __restrict__ out) {
  const int k = threadIdx.x;
  if (k == 0) out[0] = 0.f;   // phase2 atomicAdds into this
#pragma unroll
  for (int t = 0; t < 32; ++t)
    Wpk[t * Hh + k] = f2bf(W[k * 32 + t]);
}

// ---------------- K1: fused MFMA emissions + log_softmax, split-K ----------
// grid 1024 x 256thr. Block = rows row0..row0+15; wave wv does K quarter wv.
// A[m=lane&15][k=(lane>>4)*8+j]; B[k][n=lane&15]; C/D col=lane&15,row=q*4+r.
__global__ __launch_bounds__(256) void emis_fused_kernel(
    const float* __restrict__ hidden, const short* __restrict__ Wpk,
    const float* __restrict__ bias, float* __restrict__ logem,
    float* __restrict__ pem) {
  __shared__ float red[4 * 16 * 33];  // [wave][row][col], stride 33: 2-way max
  const int tid = threadIdx.x;
  const int wv = tid >> 6, lane = tid & 63;
  const int n = lane & 15, q = lane >> 4;
  const int row0 = blockIdx.x * 16;
  const int koff = wv * 256;

  const float* ap = hidden + (size_t)(row0 + n) * Hh + koff + 8 * q;
  const short* bpl = Wpk + n * Hh + koff + 8 * q;
  const short* bpr = Wpk + (16 + n) * Hh + koff + 8 * q;

  f32x4 d0 = {0.f, 0.f, 0.f, 0.f}, d1 = {0.f, 0.f, 0.f, 0.f};

  // 4-slot, prefetch-distance-3 pipeline (in flight ~9KB/wave).
  float4 ha[4], hb[4];
  bf16x8 wl[4], wr[4];
#pragma unroll
  for (int s = 0; s < 3; ++s) {
    const int off = s * 32;
    ha[s] = *(const float4*)(ap + off);
    hb[s] = *(const float4*)(ap + off + 4);
    wl[s] = *(const bf16x8*)(bpl + off);
    wr[s] = *(const bf16x8*)(bpr + off);
  }

#pragma unroll
  for (int kc = 0; kc < 8; ++kc) {
    const int cur = kc & 3;
    if (kc + 3 < 8) {
      const int nx = (kc + 3) & 3;
      const int off = (kc + 3) * 32;
      ha[nx] = *(const float4*)(ap + off);
      hb[nx] = *(const float4*)(ap + off + 4);
      wl[nx] = *(const bf16x8*)(bpl + off);
      wr[nx] = *(const bf16x8*)(bpr + off);
    }
    bf16x8 a;
    a[0] = f2bf(ha[cur].x); a[1] = f2bf(ha[cur].y);
    a[2] = f2bf(ha[cur].z); a[3] = f2bf(ha[cur].w);
    a[4] = f2bf(hb[cur].x); a[5] = f2bf(hb[cur].y);
    a[6] = f2bf(hb[cur].z); a[7] = f2bf(hb[cur].w);
    d0 = __builtin_amdgcn_mfma_f32_16x16x32_bf16(a, wl[cur], d0, 0, 0, 0);
    d1 = __builtin_amdgcn_mfma_f32_16x16x32_bf16(a, wr[cur], d1, 0, 0, 0);
  }

  // partials -> LDS
#pragma unroll
  for (int r = 0; r < 4; ++r) {
    red[(wv * 16 + 4 * q + r) * 33 + n] = d0[r];
    red[(wv * 16 + 4 * q + r) * 33 + 16 + n] = d1[r];
  }
  __syncthreads();

  // combine + softmax: thread = (row = tid>>4, cols c0 = tid&15, c1 = c0+16).
  const int row = tid >> 4, c0 = tid & 15, c1 = 16 + c0;
  float v0 = 0.f, v1 = 0.f;
#pragma unroll
  for (int w = 0; w < 4; ++w) {
    v0 += red[(w * 16 + row) * 33 + c0];
    v1 += red[(w * 16 + row) * 33 + c1];
  }
  const float L0 = v0 + bias[c0], L1 = v1 + bias[c1];
  float mx = fmaxf(L0, L1);
#pragma unroll
  for (int d = 8; d >= 1; d >>= 1) mx = fmaxf(mx, __shfl_xor(mx, d, 16));
  float se = __expf(L0 - mx) + __expf(L1 - mx);
#pragma unroll
  for (int d = 8; d >= 1; d >>= 1) se += __shfl_xor(se, d, 16);
  const float corr = mx + __logf(se);
  const float lg0 = L0 - corr, lg1 = L1 - corr;
  const size_t rb = (size_t)(row0 + row) * Tt;
  logem[rb + c0] = lg0;
  logem[rb + c1] = lg1;
  pem[rb + c0] = __expf(lg0);
  pem[rb + c1] = __expf(lg1);
}

// ---------------- K2: chunk transfer matrices via MFMA ----------------
// nst derived from mask ballot (prefix mask) — no lenw dependency.
__global__ __launch_bounds__(256) void chunk_kernel(
    const float* __restrict__ pem, const float* __restrict__ trans,
    const int* __restrict__ mask, float* __restrict__ ecT,
    float* __restrict__ moff) {
  __shared__ __align__(16) float Pbuf[4 * 32 * 36];
  const int tid = threadIdx.x;
  const int wv = tid >> 6, lane = tid & 63;
  const int n = lane & 15, q = lane >> 4;
  const int chunk = blockIdx.x * 4 + wv;
  const int b = chunk >> 5, cc = chunk & 31;
  float* P = Pbuf + wv * 32 * 36;

  float etr0[8], etr1[8];
#pragma unroll
  for (int jj = 0; jj < 8; ++jj) {
    etr0[jj] = __expf(trans[(8 * q + jj) * 32 + n]);
    etr1[jj] = __expf(trans[(8 * q + jj) * 32 + 16 + n]);
  }

  const int t0 = 1 + cc * CHUNK_L;
  const int rowbase = b * Ss + t0;
  int pred = 0;
  if (lane < 16 && t0 + lane < Ss) pred = mask[rowbase + lane];
  const unsigned long long bal = __ballot(pred != 0);
  const int nst = __popcll(bal & 0xFFFFull);  // prefix mask -> count = run length

  bf16x8 a0, a1;
#pragma unroll
  for (int jj = 0; jj < 8; ++jj) {
    a0[jj] = (n == 8 * q + jj) ? (short)0x3F80 : (short)0;
    a1[jj] = (16 + n == 8 * q + jj) ? (short)0x3F80 : (short)0;
  }

  f32x4 d00, d01, d10, d11;
  if (nst == 0) {
#pragma unroll
    for (int r = 0; r < 4; ++r) {
      d00[r] = (4 * q + r == n) ? 1.f : 0.f;
      d01[r] = 0.f;
      d10[r] = 0.f;
      d11[r] = (4 * q + r == n) ? 1.f : 0.f;
    }
  }
  float em0 = 0.f, em1 = 0.f;
  if (nst > 0) {
    em0 = pem[(size_t)rowbase * Tt + n];
    em1 = pem[(size_t)rowbase * Tt + 16 + n];
  }
  for (int st = 0; st < nst; ++st) {
    float em0n = 0.f, em1n = 0.f;
    if (st + 1 < nst) {
      em0n = pem[(size_t)(rowbase + st + 1) * Tt + n];
      em1n = pem[(size_t)(rowbase + st + 1) * Tt + 16 + n];
    }
    bf16x8 bL, bR;
#pragma unroll
    for (int jj = 0; jj < 8; ++jj) {
      bL[jj] = f2bf(etr0[jj] * em0);
      bR[jj] = f2bf(etr1[jj] * em1);
    }
    const f32x4 z = {0.f, 0.f, 0.f, 0.f};
    d00 = __builtin_amdgcn_mfma_f32_16x16x32_bf16(a0, bL, z, 0, 0, 0);
    d01 = __builtin_amdgcn_mfma_f32_16x16x32_bf16(a0, bR, z, 0, 0, 0);
    d10 = __builtin_amdgcn_mfma_f32_16x16x32_bf16(a1, bL, z, 0, 0, 0);
    d11 = __builtin_amdgcn_mfma_f32_16x16x32_bf16(a1, bR, z, 0, 0, 0);
    if (st + 1 < nst) {
#pragma unroll
      for (int r = 0; r < 4; ++r) {
        P[(4 * q + r) * 36 + n] = d00[r];
        P[(4 * q + r) * 36 + 16 + n] = d01[r];
        P[(16 + 4 * q + r) * 36 + n] = d10[r];
        P[(16 + 4 * q + r) * 36 + 16 + n] = d11[r];
      }
      __builtin_amdgcn_s_waitcnt(0);
      const float4 lo0 = *(const float4*)&P[n * 36 + 8 * q];
      const float4 lo1 = *(const float4*)&P[n * 36 + 8 * q + 4];
      const float4 hi0 = *(const float4*)&P[(16 + n) * 36 + 8 * q];
      const float4 hi1 = *(const float4*)&P[(16 + n) * 36 + 8 * q + 4];
      a0[0] = f2bf(lo0.x); a0[1] = f2bf(lo0.y); a0[2] = f2bf(lo0.z); a0[3] = f2bf(lo0.w);
      a0[4] = f2bf(lo1.x); a0[5] = f2bf(lo1.y); a0[6] = f2bf(lo1.z); a0[7] = f2bf(lo1.w);
      a1[0] = f2bf(hi0.x); a1[1] = f2bf(hi0.y); a1[2] = f2bf(hi0.z); a1[3] = f2bf(hi0.w);
      a1[4] = f2bf(hi1.x); a1[5] = f2bf(hi1.y); a1[6] = f2bf(hi1.z); a1[7] = f2bf(hi1.w);
    }
    em0 = em0n; em1 = em1n;
  }

  float lg0[4], lg1[4], iv0[4], iv1[4];
#pragma unroll
  for (int r = 0; r < 4; ++r) {
    float m0v = fmaxf(d00[r], d01[r]);
    float m1v = fmaxf(d10[r], d11[r]);
#pragma unroll
    for (int d = 8; d >= 1; d >>= 1) {
      m0v = fmaxf(m0v, __shfl_xor(m0v, d, 16));
      m1v = fmaxf(m1v, __shfl_xor(m1v, d, 16));
    }
    m0v = fmaxf(m0v, 1e-37f);
    m1v = fmaxf(m1v, 1e-37f);
    lg0[r] = __logf(m0v); iv0[r] = __builtin_amdgcn_rcpf(m0v);
    lg1[r] = __logf(m1v); iv1[r] = __builtin_amdgcn_rcpf(m1v);
  }
  float* E = ecT + (size_t)(b * NCHUNK + cc) * 32 * 32;
  {
    float4 s;
    s = make_float4(d00[0] * iv0[0], d00[1] * iv0[1], d00[2] * iv0[2], d00[3] * iv0[3]);
    *(float4*)&E[n * 32 + 4 * q] = s;
    s = make_float4(d10[0] * iv1[0], d10[1] * iv1[1], d10[2] * iv1[2], d10[3] * iv1[3]);
    *(float4*)&E[n * 32 + 16 + 4 * q] = s;
    s = make_float4(d01[0] * iv0[0], d01[1] * iv0[1], d01[2] * iv0[2], d01[3] * iv0[3]);
    *(float4*)&E[(16 + n) * 32 + 4 * q] = s;
    s = make_float4(d11[0] * iv1[0], d11[1] * iv1[1], d11[2] * iv1[2], d11[3] * iv1[3]);
    *(float4*)&E[(16 + n) * 32 + 16 + 4 * q] = s;
  }
  if (n == 0) {
    float* Mo = moff + (size_t)(b * NCHUNK + cc) * 32;
    *(float4*)&Mo[4 * q] = make_float4(lg0[0], lg0[1], lg0[2], lg0[3]);
    *(float4*)&Mo[16 + 4 * q] = make_float4(lg1[0], lg1[1], lg1[2], lg1[3]);
  }
}

// ---------------- K3: phase-2 sweep + fused numerator, one wave/batch -------
__global__ __launch_bounds__(64) void phase2_kernel(
    const float* __restrict__ logem, const float* __restrict__ start_trans,
    const float* __restrict__ end_trans, const float* __restrict__ ecT,
    const float* __restrict__ moff, const float* __restrict__ trans,
    const int* __restrict__ tags, const int* __restrict__ mask,
    float* __restrict__ out) {
  const int b = blockIdx.x;
  const int lane = threadIdx.x;
  const int j = lane & 31;
  __shared__ __align__(16) float qlds[32];

  // ---- fused CRF numerator + length (all 64 lanes, width-64 reduce) ----
  const int base_row = b * Ss;
  int lensum = 0;
  float snum = 0.f;
#pragma unroll
  for (int k = 0; k < 8; ++k) {
    const int ss = lane + 64 * k;
    const int m = mask[base_row + ss];
    lensum += m;
    if (m) {
      const int tg = tags[base_row + ss];
      snum += logem[(size_t)(base_row + ss) * Tt + tg];
      if (ss > 0) snum += trans[tags[base_row + ss - 1] * Tt + tg];
    }
  }
#pragma unroll
  for (int d = 32; d >= 1; d >>= 1) {
    snum += __shfl_xor(snum, d);
    lensum += __shfl_xor(lensum, d);
  }

  // ---- chunk-matrix sweep ----
  const float* base = ecT + (size_t)b * NCHUNK * 32 * 32;
  const float* mbase = moff + (size_t)b * NCHUNK * 32;

  float4 M[8], N[8];
  const float* r0 = base + j * 32;
#pragma unroll
  for (int k = 0; k < 8; ++k) M[k] = *(const float4*)(r0 + 4 * k);
  float mo_cur = mbase[j];

  float al0 = start_trans[j] + logem[(size_t)base_row * Tt + j];
  float m0 = al0;
#pragma unroll
  for (int d = 16; d >= 1; d >>= 1) m0 = fmaxf(m0, __shfl_xor(m0, d, 32));
  float a = __expf(al0 - m0);
  float Mb = m0;
  const float eend = __expf(end_trans[j]);

  float mo_next = 0.f;
  for (int c = 0; c < NCHUNK; ++c) {
    if (c + 1 < NCHUNK) {
      const float* rn = base + ((c + 1) * 32 + j) * 32;
#pragma unroll
      for (int k = 0; k < 8; ++k) N[k] = *(const float4*)(rn + 4 * k);
      mo_next = mbase[(c + 1) * 32 + j];
    }
    float mom = mo_cur;
#pragma unroll
    for (int d = 16; d >= 1; d >>= 1) mom = fmaxf(mom, __shfl_xor(mom, d, 32));
    float qv = a * __expf(mo_cur - mom);
    if (lane < 32) qlds[j] = qv;
    __builtin_amdgcn_s_waitcnt(0);
    float s = 0.f;
#pragma unroll
    for (int k = 0; k < 8; ++k) {
      const float4 q4 = *(const float4*)(qlds + 4 * k);
      s = fmaf(q4.x, M[k].x, s);
      s = fmaf(q4.y, M[k].y, s);
      s = fmaf(q4.z, M[k].z, s);
      s = fmaf(q4.w, M[k].w, s);
    }
    float m = s;
#pragma unroll
    for (int d = 16; d >= 1; d >>= 1) m = fmaxf(m, __shfl_xor(m, d, 32));
    m = fmaxf(m, 1e-30f);
    a = s * __builtin_amdgcn_rcpf(m);
    Mb += mom + __logf(m);
#pragma unroll
    for (int k = 0; k < 8; ++k) M[k] = N[k];
    mo_cur = mo_next;
  }
  float z = a * eend;
#pragma unroll
  for (int d = 16; d >= 1; d >>= 1) z += __shfl_xor(z, d, 32);
  if (lane == 0) {
    const float numfull = snum + start_trans[tags[base_row]] +
                          end_trans[tags[base_row + lensum - 1]];
    const float denom = Mb + __logf(z);
    atomicAdd(out, -(numfull - denom) * (1.0f / 32.0f));
  }
}

extern "C" void kernel_launch(void* const* d_in, const int* in_sizes, int n_in,
                              void* d_out, int out_size, void* d_ws, size_t ws_size,
                              hipStream_t stream) {
  const float* hidden = (const float*)d_in[0];
  const float* W = (const float*)d_in[1];
  const float* bias = (const float*)d_in[2];
  const float* start_trans = (const float*)d_in[3];
  const float* end_trans = (const float*)d_in[4];
  const float* trans = (const float*)d_in[5];
  const int* tags = (const int*)d_in[6];
  const int* mask = (const int*)d_in[7];
  float* out = (float*)d_out;

  float* logem = (float*)d_ws;                       // 524288
  float* pem = logem + (size_t)NROWS * Tt;           // 524288
  float* ecT = pem + (size_t)NROWS * Tt;             // 1048576
  float* moff = ecT + (size_t)Bb * NCHUNK * 32 * 32; // 32768
  short* Wpk = (short*)(moff + (size_t)Bb * NCHUNK * 32);  // 32768 shorts

  wpack_kernel<<<1, 1024, 0, stream>>>(W, Wpk, out);  // also zeroes out
  emis_fused_kernel<<<NROWS / 16, 256, 0, stream>>>(hidden, Wpk, bias, logem, pem);
  chunk_kernel<<<Bb * NCHUNK / 4, 256, 0, stream>>>(pem, trans, mask, ecT, moff);
  phase2_kernel<<<Bb, 64, 0, stream>>>(logem, start_trans, end_trans, ecT, moff,
                                       trans, tags, mask, out);
}

// Round 9
// 164.275 us; speedup vs baseline: 1.5164x; 1.0306x over previous
//
#include <hip/hip_runtime.h>
#include <hip/hip_bf16.h>

// BertCRFTagger — B=32, S=512, H=1024, T=32.
//  K0 wpack:      W -> bf16 transposed [t][k]; thread 0 zeroes out.
//  K1 emis_fused: MFMA GEMV + fused log_softmax, split-K x4.
//                 R9: hidden staged to LDS in A-FRAGMENT ORDER as bf16
//                 (coalesced row loads, XOR-swizzled 8B writes = 2-way free;
//                 MFMA loop = 1 ds_read_b128 + 2 L1-hot W loads per kc).
//                 R8's direct-global version issued 16-segment scattered
//                 loads per instr + 64 f2bf/lane on the critical path.
//  K2 chunk:      MFMA chunk transfer matrices; nst from mask ballot.
//  K3 phase2:     one wave/batch: fused numerator + prefetched chunk sweep.

#define Bb 32
#define Ss 512
#define Hh 1024
#define Tt 32
#define NROWS (Bb*Ss)          // 16384
#define NCHUNK 32
#define CHUNK_L 16

typedef __attribute__((ext_vector_type(8))) short bf16x8;
typedef __attribute__((ext_vector_type(4))) float f32x4;

__device__ __forceinline__ short f2bf(float f) {  // RNE fp32->bf16
  union { float f; unsigned u; } v; v.f = f;
  unsigned u = v.u;
  return (short)((u + 0x7FFFu + ((u >> 16) & 1u)) >> 16);
}

// ---------------- K0: pack W -> bf16 [t][k] + zero out ----------------
__global__ __launch_bounds__(1024) void wpack_kernel(
    const float* __restrict__ W, short* __restrict__ Wpk,
    float* __restrict__ out) {
  const int k = threadIdx.x;
  if (k == 0) out[0] = 0.f;   // phase2 atomicAdds into this
#pragma unroll
  for (int t = 0; t < 32; ++t)
    Wpk[t * Hh + k] = f2bf(W[k * 32 + t]);
}

// ---------------- K1: fused MFMA emissions + log_softmax, split-K ----------
// grid 1024 x 256thr. Block = rows row0..row0+15; wave wv does K quarter wv.
// A[m=lane&15][k=(lane>>4)*8+j]; B[k][n=lane&15]; C/D col=lane&15,row=q*4+r.
// Stage layout: byte addr = wv*8192 + kc*1024 + (((n*4+q)*16) ^ (kc*32)) + j*2.
__global__ __launch_bounds__(256) void emis_fused_kernel(
    const float* __restrict__ hidden, const short* __restrict__ Wpk,
    const float* __restrict__ bias, float* __restrict__ logem,
    float* __restrict__ pem) {
  __shared__ __align__(16) char smem[32768];  // stage (bf16) / red (aliased)
  float* red = (float*)smem;                  // [wave][row][col] stride 33
  const int tid = threadIdx.x;
  const int wv = tid >> 6, lane = tid & 63;
  const int n = lane & 15, q = lane >> 4;
  const int row0 = blockIdx.x * 16;
  const int koff = wv * 256;

  // ---- stage: thread t owns k0=4t of each of the 16 rows ----
  {
    const int swv = tid >> 6;           // k0>>8
    const int skc = (tid >> 3) & 7;     // (k0>>5)&7
    const int sq = (tid >> 1) & 3;      // (k0>>3)&3
    const int sj0 = (tid & 1) * 4;      // k0&7
    const int rbase = swv * 8192 + skc * 1024 + sj0 * 2;
    const int uxor = skc * 32;
    const float* hp = hidden + (size_t)row0 * Hh + 4 * tid;
#pragma unroll
    for (int i = 0; i < 16; ++i) {
      const float4 v = *(const float4*)(hp + (size_t)i * Hh);
      uint2 u;
      u.x = (unsigned short)f2bf(v.x) | ((unsigned)(unsigned short)f2bf(v.y) << 16);
      u.y = (unsigned short)f2bf(v.z) | ((unsigned)(unsigned short)f2bf(v.w) << 16);
      const int unit = ((i * 4 + sq) * 16) ^ uxor;
      *(uint2*)(smem + rbase + unit - sj0 * 2 + sj0 * 2 + (unit ? 0 : 0)) = u;  // addr below
      // NOTE: unit already excludes sj0; full addr = swv*8192+skc*1024+unit+sj0*2
    }
  }
  __syncthreads();

  // ---- MFMA loop: 1 ds_read_b128 (A) + 2 global 16B (W) per kc ----
  const short* bpl = Wpk + n * Hh + koff;
  const short* bpr = Wpk + (16 + n) * Hh + koff;
  f32x4 d0 = {0.f, 0.f, 0.f, 0.f}, d1 = {0.f, 0.f, 0.f, 0.f};
#pragma unroll
  for (int kc = 0; kc < 8; ++kc) {
    const int aaddr = wv * 8192 + kc * 1024 + (((n * 4 + q) * 16) ^ (kc * 32));
    const bf16x8 a = *(const bf16x8*)(smem + aaddr);
    const bf16x8 wl = *(const bf16x8*)(bpl + kc * 32 + 8 * q);
    const bf16x8 wr = *(const bf16x8*)(bpr + kc * 32 + 8 * q);
    d0 = __builtin_amdgcn_mfma_f32_16x16x32_bf16(a, wl, d0, 0, 0, 0);
    d1 = __builtin_amdgcn_mfma_f32_16x16x32_bf16(a, wr, d1, 0, 0, 0);
  }
  __syncthreads();  // stage dead -> red may alias

  // partials -> LDS
#pragma unroll
  for (int r = 0; r < 4; ++r) {
    red[(wv * 16 + 4 * q + r) * 33 + n] = d0[r];
    red[(wv * 16 + 4 * q + r) * 33 + 16 + n] = d1[r];
  }
  __syncthreads();

  // combine + softmax: thread = (row = tid>>4, cols c0 = tid&15, c1 = c0+16).
  const int row = tid >> 4, c0 = tid & 15, c1 = 16 + c0;
  float v0 = 0.f, v1 = 0.f;
#pragma unroll
  for (int w = 0; w < 4; ++w) {
    v0 += red[(w * 16 + row) * 33 + c0];
    v1 += red[(w * 16 + row) * 33 + c1];
  }
  const float L0 = v0 + bias[c0], L1 = v1 + bias[c1];
  float mx = fmaxf(L0, L1);
#pragma unroll
  for (int d = 8; d >= 1; d >>= 1) mx = fmaxf(mx, __shfl_xor(mx, d, 16));
  float se = __expf(L0 - mx) + __expf(L1 - mx);
#pragma unroll
  for (int d = 8; d >= 1; d >>= 1) se += __shfl_xor(se, d, 16);
  const float corr = mx + __logf(se);
  const float lg0 = L0 - corr, lg1 = L1 - corr;
  const size_t rb = (size_t)(row0 + row) * Tt;
  logem[rb + c0] = lg0;
  logem[rb + c1] = lg1;
  pem[rb + c0] = __expf(lg0);
  pem[rb + c1] = __expf(lg1);
}

// ---------------- K2: chunk transfer matrices via MFMA ----------------
__global__ __launch_bounds__(256) void chunk_kernel(
    const float* __restrict__ pem, const float* __restrict__ trans,
    const int* __restrict__ mask, float* __restrict__ ecT,
    float* __restrict__ moff) {
  __shared__ __align__(16) float Pbuf[4 * 32 * 36];
  const int tid = threadIdx.x;
  const int wv = tid >> 6, lane = tid & 63;
  const int n = lane & 15, q = lane >> 4;
  const int chunk = blockIdx.x * 4 + wv;
  const int b = chunk >> 5, cc = chunk & 31;
  float* P = Pbuf + wv * 32 * 36;

  float etr0[8], etr1[8];
#pragma unroll
  for (int jj = 0; jj < 8; ++jj) {
    etr0[jj] = __expf(trans[(8 * q + jj) * 32 + n]);
    etr1[jj] = __expf(trans[(8 * q + jj) * 32 + 16 + n]);
  }

  const int t0 = 1 + cc * CHUNK_L;
  const int rowbase = b * Ss + t0;
  int pred = 0;
  if (lane < 16 && t0 + lane < Ss) pred = mask[rowbase + lane];
  const unsigned long long bal = __ballot(pred != 0);
  const int nst = __popcll(bal & 0xFFFFull);

  bf16x8 a0, a1;
#pragma unroll
  for (int jj = 0; jj < 8; ++jj) {
    a0[jj] = (n == 8 * q + jj) ? (short)0x3F80 : (short)0;
    a1[jj] = (16 + n == 8 * q + jj) ? (short)0x3F80 : (short)0;
  }

  f32x4 d00, d01, d10, d11;
  if (nst == 0) {
#pragma unroll
    for (int r = 0; r < 4; ++r) {
      d00[r] = (4 * q + r == n) ? 1.f : 0.f;
      d01[r] = 0.f;
      d10[r] = 0.f;
      d11[r] = (4 * q + r == n) ? 1.f : 0.f;
    }
  }
  float em0 = 0.f, em1 = 0.f;
  if (nst > 0) {
    em0 = pem[(size_t)rowbase * Tt + n];
    em1 = pem[(size_t)rowbase * Tt + 16 + n];
  }
  for (int st = 0; st < nst; ++st) {
    float em0n = 0.f, em1n = 0.f;
    if (st + 1 < nst) {
      em0n = pem[(size_t)(rowbase + st + 1) * Tt + n];
      em1n = pem[(size_t)(rowbase + st + 1) * Tt + 16 + n];
    }
    bf16x8 bL, bR;
#pragma unroll
    for (int jj = 0; jj < 8; ++jj) {
      bL[jj] = f2bf(etr0[jj] * em0);
      bR[jj] = f2bf(etr1[jj] * em1);
    }
    const f32x4 z = {0.f, 0.f, 0.f, 0.f};
    d00 = __builtin_amdgcn_mfma_f32_16x16x32_bf16(a0, bL, z, 0, 0, 0);
    d01 = __builtin_amdgcn_mfma_f32_16x16x32_bf16(a0, bR, z, 0, 0, 0);
    d10 = __builtin_amdgcn_mfma_f32_16x16x32_bf16(a1, bL, z, 0, 0, 0);
    d11 = __builtin_amdgcn_mfma_f32_16x16x32_bf16(a1, bR, z, 0, 0, 0);
    if (st + 1 < nst) {
#pragma unroll
      for (int r = 0; r < 4; ++r) {
        P[(4 * q + r) * 36 + n] = d00[r];
        P[(4 * q + r) * 36 + 16 + n] = d01[r];
        P[(16 + 4 * q + r) * 36 + n] = d10[r];
        P[(16 + 4 * q + r) * 36 + 16 + n] = d11[r];
      }
      __builtin_amdgcn_s_waitcnt(0);
      const float4 lo0 = *(const float4*)&P[n * 36 + 8 * q];
      const float4 lo1 = *(const float4*)&P[n * 36 + 8 * q + 4];
      const float4 hi0 = *(const float4*)&P[(16 + n) * 36 + 8 * q];
      const float4 hi1 = *(const float4*)&P[(16 + n) * 36 + 8 * q + 4];
      a0[0] = f2bf(lo0.x); a0[1] = f2bf(lo0.y); a0[2] = f2bf(lo0.z); a0[3] = f2bf(lo0.w);
      a0[4] = f2bf(lo1.x); a0[5] = f2bf(lo1.y); a0[6] = f2bf(lo1.z); a0[7] = f2bf(lo1.w);
      a1[0] = f2bf(hi0.x); a1[1] = f2bf(hi0.y); a1[2] = f2bf(hi0.z); a1[3] = f2bf(hi0.w);
      a1[4] = f2bf(hi1.x); a1[5] = f2bf(hi1.y); a1[6] = f2bf(hi1.z); a1[7] = f2bf(hi1.w);
    }
    em0 = em0n; em1 = em1n;
  }

  float lg0[4], lg1[4], iv0[4], iv1[4];
#pragma unroll
  for (int r = 0; r < 4; ++r) {
    float m0v = fmaxf(d00[r], d01[r]);
    float m1v = fmaxf(d10[r], d11[r]);
#pragma unroll
    for (int d = 8; d >= 1; d >>= 1) {
      m0v = fmaxf(m0v, __shfl_xor(m0v, d, 16));
      m1v = fmaxf(m1v, __shfl_xor(m1v, d, 16));
    }
    m0v = fmaxf(m0v, 1e-37f);
    m1v = fmaxf(m1v, 1e-37f);
    lg0[r] = __logf(m0v); iv0[r] = __builtin_amdgcn_rcpf(m0v);
    lg1[r] = __logf(m1v); iv1[r] = __builtin_amdgcn_rcpf(m1v);
  }
  float* E = ecT + (size_t)(b * NCHUNK + cc) * 32 * 32;
  {
    float4 s;
    s = make_float4(d00[0] * iv0[0], d00[1] * iv0[1], d00[2] * iv0[2], d00[3] * iv0[3]);
    *(float4*)&E[n * 32 + 4 * q] = s;
    s = make_float4(d10[0] * iv1[0], d10[1] * iv1[1], d10[2] * iv1[2], d10[3] * iv1[3]);
    *(float4*)&E[n * 32 + 16 + 4 * q] = s;
    s = make_float4(d01[0] * iv0[0], d01[1] * iv0[1], d01[2] * iv0[2], d01[3] * iv0[3]);
    *(float4*)&E[(16 + n) * 32 + 4 * q] = s;
    s = make_float4(d11[0] * iv1[0], d11[1] * iv1[1], d11[2] * iv1[2], d11[3] * iv1[3]);
    *(float4*)&E[(16 + n) * 32 + 16 + 4 * q] = s;
  }
  if (n == 0) {
    float* Mo = moff + (size_t)(b * NCHUNK + cc) * 32;
    *(float4*)&Mo[4 * q] = make_float4(lg0[0], lg0[1], lg0[2], lg0[3]);
    *(float4*)&Mo[16 + 4 * q] = make_float4(lg1[0], lg1[1], lg1[2], lg1[3]);
  }
}

// ---------------- K3: phase-2 sweep + fused numerator, one wave/batch -------
__global__ __launch_bounds__(64) void phase2_kernel(
    const float* __restrict__ logem, const float* __restrict__ start_trans,
    const float* __restrict__ end_trans, const float* __restrict__ ecT,
    const float* __restrict__ moff, const float* __restrict__ trans,
    const int* __restrict__ tags, const int* __restrict__ mask,
    float* __restrict__ out) {
  const int b = blockIdx.x;
  const int lane = threadIdx.x;
  const int j = lane & 31;
  __shared__ __align__(16) float qlds[32];

  const int base_row = b * Ss;
  int lensum = 0;
  float snum = 0.f;
#pragma unroll
  for (int k = 0; k < 8; ++k) {
    const int ss = lane + 64 * k;
    const int m = mask[base_row + ss];
    lensum += m;
    if (m) {
      const int tg = tags[base_row + ss];
      snum += logem[(size_t)(base_row + ss) * Tt + tg];
      if (ss > 0) snum += trans[tags[base_row + ss - 1] * Tt + tg];
    }
  }
#pragma unroll
  for (int d = 32; d >= 1; d >>= 1) {
    snum += __shfl_xor(snum, d);
    lensum += __shfl_xor(lensum, d);
  }

  const float* base = ecT + (size_t)b * NCHUNK * 32 * 32;
  const float* mbase = moff + (size_t)b * NCHUNK * 32;

  float4 M[8], N[8];
  const float* r0 = base + j * 32;
#pragma unroll
  for (int k = 0; k < 8; ++k) M[k] = *(const float4*)(r0 + 4 * k);
  float mo_cur = mbase[j];

  float al0 = start_trans[j] + logem[(size_t)base_row * Tt + j];
  float m0 = al0;
#pragma unroll
  for (int d = 16; d >= 1; d >>= 1) m0 = fmaxf(m0, __shfl_xor(m0, d, 32));
  float a = __expf(al0 - m0);
  float Mb = m0;
  const float eend = __expf(end_trans[j]);

  float mo_next = 0.f;
  for (int c = 0; c < NCHUNK; ++c) {
    if (c + 1 < NCHUNK) {
      const float* rn = base + ((c + 1) * 32 + j) * 32;
#pragma unroll
      for (int k = 0; k < 8; ++k) N[k] = *(const float4*)(rn + 4 * k);
      mo_next = mbase[(c + 1) * 32 + j];
    }
    float mom = mo_cur;
#pragma unroll
    for (int d = 16; d >= 1; d >>= 1) mom = fmaxf(mom, __shfl_xor(mom, d, 32));
    float qv = a * __expf(mo_cur - mom);
    if (lane < 32) qlds[j] = qv;
    __builtin_amdgcn_s_waitcnt(0);
    float s = 0.f;
#pragma unroll
    for (int k = 0; k < 8; ++k) {
      const float4 q4 = *(const float4*)(qlds + 4 * k);
      s = fmaf(q4.x, M[k].x, s);
      s = fmaf(q4.y, M[k].y, s);
      s = fmaf(q4.z, M[k].z, s);
      s = fmaf(q4.w, M[k].w, s);
    }
    float m = s;
#pragma unroll
    for (int d = 16; d >= 1; d >>= 1) m = fmaxf(m, __shfl_xor(m, d, 32));
    m = fmaxf(m, 1e-30f);
    a = s * __builtin_amdgcn_rcpf(m);
    Mb += mom + __logf(m);
#pragma unroll
    for (int k = 0; k < 8; ++k) M[k] = N[k];
    mo_cur = mo_next;
  }
  float z = a * eend;
#pragma unroll
  for (int d = 16; d >= 1; d >>= 1) z += __shfl_xor(z, d, 32);
  if (lane == 0) {
    const float numfull = snum + start_trans[tags[base_row]] +
                          end_trans[tags[base_row + lensum - 1]];
    const float denom = Mb + __logf(z);
    atomicAdd(out, -(numfull - denom) * (1.0f / 32.0f));
  }
}

extern "C" void kernel_launch(void* const* d_in, const int* in_sizes, int n_in,
                              void* d_out, int out_size, void* d_ws, size_t ws_size,
                              hipStream_t stream) {
  const float* hidden = (const float*)d_in[0];
  const float* W = (const float*)d_in[1];
  const float* bias = (const float*)d_in[2];
  const float* start_trans = (const float*)d_in[3];
  const float* end_trans = (const float*)d_in[4];
  const float* trans = (const float*)d_in[5];
  const int* tags = (const int*)d_in[6];
  const int* mask = (const int*)d_in[7];
  float* out = (float*)d_out;

  float* logem = (float*)d_ws;                       // 524288
  float* pem = logem + (size_t)NROWS * Tt;           // 524288
  float* ecT = pem + (size_t)NROWS * Tt;             // 1048576
  float* moff = ecT + (size_t)Bb * NCHUNK * 32 * 32; // 32768
  short* Wpk = (short*)(moff + (size_t)Bb * NCHUNK * 32);  // 32768 shorts

  wpack_kernel<<<1, 1024, 0, stream>>>(W, Wpk, out);  // also zeroes out
  emis_fused_kernel<<<NROWS / 16, 256, 0, stream>>>(hidden, Wpk, bias, logem, pem);
  chunk_kernel<<<Bb * NCHUNK / 4, 256, 0, stream>>>(pem, trans, mask, ecT, moff);
  phase2_kernel<<<Bb, 64, 0, stream>>>(logem, start_trans, end_trans, ecT, moff,
                                       trans, tags, mask, out);
}